// Round 6
// baseline (124.002 us; speedup 1.0000x reference)
//
#include <hip/hip_runtime.h>
#include <hip/hip_bf16.h>

typedef __bf16 bf16;
typedef __attribute__((ext_vector_type(8))) __bf16 bf16x8;
typedef __attribute__((ext_vector_type(4))) __bf16 bf16x4;
typedef __attribute__((ext_vector_type(4))) float f32x4;

#define NEGV (-1e18f)
#define LOG2E 1.4426950408889634f

__device__ __forceinline__ bf16 f2b(float f) {
    unsigned u = __builtin_bit_cast(unsigned, f);
    u += 0x7fffu + ((u >> 16) & 1u);
    unsigned short h = (unsigned short)(u >> 16);
    return __builtin_bit_cast(bf16, h);
}

__device__ __forceinline__ f32x4 mfma16(bf16x8 a, bf16x8 b, f32x4 c) {
    return __builtin_amdgcn_mfma_f32_16x16x32_bf16(a, b, c, 0, 0, 0);
}

__device__ __forceinline__ void gl16(const void* g, void* l) {
    __builtin_amdgcn_global_load_lds((const __attribute__((address_space(1))) void*)g,
                                     (__attribute__((address_space(3))) void*)l, 16, 0, 0);
}

// ---------------------------------------------------------------------------
// Weight transpose + f32->bf16 convert: out[w][n][k] = in[w][k][n]
// ---------------------------------------------------------------------------
__global__ __launch_bounds__(256) void wconv(const float* __restrict__ W0,
                                             const float* __restrict__ W1,
                                             const float* __restrict__ W2,
                                             const float* __restrict__ W3,
                                             bf16* __restrict__ out) {
    __shared__ float tile[64][65];
    const float* Ws[4] = {W0, W1, W2, W3};
    const float* W = Ws[blockIdx.z];
    bf16* O = out + ((size_t)blockIdx.z << 20);
    int t = threadIdx.x;
    int k0 = blockIdx.x * 64, n0 = blockIdx.y * 64;
#pragma unroll
    for (int p = 0; p < 4; p++) {
        int r = (t >> 4) + p * 16, c = (t & 15) * 4;
        float4 v = *(const float4*)&W[(size_t)(k0 + r) * 1024 + n0 + c];
        tile[r][c] = v.x; tile[r][c + 1] = v.y; tile[r][c + 2] = v.z; tile[r][c + 3] = v.w;
    }
    __syncthreads();
#pragma unroll
    for (int p = 0; p < 4; p++) {
        int r = (t >> 4) + p * 16, c = (t & 15) * 4;
        bf16x4 o;
        o[0] = f2b(tile[c][r]); o[1] = f2b(tile[c + 1][r]);
        o[2] = f2b(tile[c + 2][r]); o[3] = f2b(tile[c + 3][r]);
        *(bf16x4*)&O[(size_t)(n0 + r) * 1024 + k0 + c] = o;
    }
}

// ---------------------------------------------------------------------------
// Projection GEMM, double-buffered 2-phase (T3-minimum). 128x128 tile, BK=64,
// 4 waves. Per iter: STAGE(buf^1, t+1) [gl16 B pre-swizzled-src + cvt A
// ds_write] -> ds_read frags buf[cur] -> 32 MFMA -> one barrier -> flip.
// A (f32) reg-prefetched ~1.5 iters ahead. LDS 64KB -> 2 blocks/CU.
// z=0: Qw*0.125, z=1: Kw, z=2: VtG (transposed out).
// ---------------------------------------------------------------------------
__global__ __launch_bounds__(256, 2) void gemm_proj(const float* __restrict__ Qf,
                                                    const float* __restrict__ Kf,
                                                    const float* __restrict__ Vf,
                                                    const bf16* __restrict__ WtQ,
                                                    bf16* __restrict__ Qw,
                                                    bf16* __restrict__ Kw,
                                                    bf16* __restrict__ VtG) {
    __shared__ bf16 As[2][128 * 64];
    __shared__ bf16 Bs[2][128 * 64];
    char* AsB = (char*)As;
    char* BsB = (char*)Bs;
    const int BUFSZ = 128 * 64 * 2;   // bytes per buffer
    int t = threadIdx.x;
    int m0 = blockIdx.x * 128, n0 = blockIdx.y * 128;
    int z = blockIdx.z;
    const float* A = (z == 0) ? Qf : (z == 1) ? Kf : Vf;
    const bf16* Bt = WtQ + ((size_t)z << 20);
    int wid = t >> 6, lane = t & 63;
    int wr = wid >> 1, wc = wid & 1, lr = lane & 15, lg = lane >> 4;
    f32x4 zero = {0.f, 0.f, 0.f, 0.f};
    f32x4 acc[4][4];
#pragma unroll
    for (int m = 0; m < 4; m++)
#pragma unroll
        for (int n = 0; n < 4; n++) acc[m][n] = zero;

    // per-thread staging coords (4 chunks)
    int sc_[4], srow[4], sq[4];
#pragma unroll
    for (int i = 0; i < 4; i++) {
        int c = wid * 256 + i * 64 + lane;
        sc_[i] = c; srow[i] = c >> 3; sq[i] = c & 7;
    }

    float4 pa[4][2];
#define LOADA(K0)                                                              \
    {                                                                          \
        _Pragma("unroll") for (int i = 0; i < 4; i++) {                        \
            const float* src = &A[(size_t)(m0 + srow[i]) * 1024 + (K0) + sq[i] * 8]; \
            pa[i][0] = *(const float4*)src;                                    \
            pa[i][1] = *(const float4*)(src + 4);                              \
        }                                                                      \
    }
#define STAGE_B(BUF, K0)                                                       \
    {                                                                          \
        _Pragma("unroll") for (int i = 0; i < 4; i++) {                        \
            int q = sq[i] ^ (srow[i] & 7);                                     \
            gl16(&Bt[(size_t)(n0 + srow[i]) * 1024 + (K0) + q * 8],            \
                 (void*)&Bs[BUF][sc_[i] * 8]);                                 \
        }                                                                      \
    }
#define WRITE_A(BUF)                                                           \
    {                                                                          \
        _Pragma("unroll") for (int i = 0; i < 4; i++) {                        \
            bf16x8 o;                                                          \
            o[0] = f2b(pa[i][0].x); o[1] = f2b(pa[i][0].y);                    \
            o[2] = f2b(pa[i][0].z); o[3] = f2b(pa[i][0].w);                    \
            o[4] = f2b(pa[i][1].x); o[5] = f2b(pa[i][1].y);                    \
            o[6] = f2b(pa[i][1].z); o[7] = f2b(pa[i][1].w);                    \
            *(bf16x8*)(AsB + (BUF) * BUFSZ +                                   \
                       ((sc_[i] * 16) ^ ((srow[i] & 7) << 4))) = o;            \
        }                                                                      \
    }

    // prologue: stage tile 0 into buf 0, prefetch tile 1 regs
    LOADA(0);
    STAGE_B(0, 0);
    WRITE_A(0);
    LOADA(64);
    __syncthreads();

    int cur = 0;
    for (int k0 = 0; k0 < 1024; k0 += 64) {
        if (k0 < 960) {
            STAGE_B(cur ^ 1, k0 + 64);
            WRITE_A(cur ^ 1);
            if (k0 < 896) LOADA(k0 + 128);
        }
#pragma unroll
        for (int kk = 0; kk < 2; kk++) {
            bf16x8 af[4], bfr[4];
#pragma unroll
            for (int m = 0; m < 4; m++) {
                int row = wr * 64 + m * 16 + lr;
                af[m] = *(const bf16x8*)(AsB + cur * BUFSZ +
                                         ((row * 128 + kk * 64 + lg * 16) ^ ((row & 7) << 4)));
            }
#pragma unroll
            for (int n = 0; n < 4; n++) {
                int row = wc * 64 + n * 16 + lr;
                bfr[n] = *(const bf16x8*)(BsB + cur * BUFSZ +
                                          ((row * 128 + kk * 64 + lg * 16) ^ ((row & 7) << 4)));
            }
#pragma unroll
            for (int m = 0; m < 4; m++)
#pragma unroll
                for (int n = 0; n < 4; n++) acc[m][n] = mfma16(af[m], bfr[n], acc[m][n]);
        }
        __syncthreads();
        cur ^= 1;
    }
#undef LOADA
#undef STAGE_B
#undef WRITE_A
#pragma unroll
    for (int n = 0; n < 4; n++) {
        int colg = n0 + wc * 64 + n * 16 + lr;
#pragma unroll
        for (int m = 0; m < 4; m++) {
            int rowg = m0 + wr * 64 + m * 16 + lg * 4;
            if (z == 2) {
                bf16x4 o;
#pragma unroll
                for (int j = 0; j < 4; j++) o[j] = f2b(acc[m][n][j]);
                *(bf16x4*)&VtG[(size_t)colg * 4096 + rowg] = o;
            } else {
                bf16* C = (z == 0) ? Qw : Kw;
                float sc = (z == 0) ? 0.125f : 1.0f;
#pragma unroll
                for (int j = 0; j < 4; j++)
                    C[(size_t)(rowg + j) * 1024 + colg] = f2b(acc[m][n][j] * sc);
            }
        }
    }
}

// ---------------------------------------------------------------------------
// Merged output + attention_weights GEMM, double-buffered 2-phase, BK=64.
// z=0: out = CTX @ Wo (f32). z=1: aw[b] = masked(Qw Kw^T)/16.
// ---------------------------------------------------------------------------
__global__ __launch_bounds__(256, 2) void gemm_oa(const bf16* __restrict__ CTX,
                                                  const bf16* __restrict__ WtO,
                                                  float* __restrict__ out,
                                                  const bf16* __restrict__ Qw,
                                                  const bf16* __restrict__ Kw,
                                                  float* __restrict__ aw,
                                                  const int* __restrict__ maskp) {
    __shared__ bf16 As[2][128 * 64];
    __shared__ bf16 Bs[2][128 * 64];
    char* AsB = (char*)As;
    char* BsB = (char*)Bs;
    const int BUFSZ = 128 * 64 * 2;
    int t = threadIdx.x;
    int z = blockIdx.z;
    int bx = blockIdx.x;
    int m0, n0 = blockIdx.y * 128;
    const bf16* A;
    const bf16* Bt;
    float* C;
    const int* mask = nullptr;
    if (z == 0) {
        m0 = bx * 128;
        A = CTX; Bt = WtO; C = out;
    } else {
        int b = bx >> 3;
        m0 = (bx & 7) * 128;
        A = Qw + ((size_t)b << 20); Bt = Kw + ((size_t)b << 20);
        C = aw + ((size_t)b << 20); mask = maskp + b * 1024;
    }
    int wid = t >> 6, lane = t & 63;
    int wr = wid >> 1, wc = wid & 1, lr = lane & 15, lg = lane >> 4;
    f32x4 zero = {0.f, 0.f, 0.f, 0.f};
    f32x4 acc[4][4];
#pragma unroll
    for (int m = 0; m < 4; m++)
#pragma unroll
        for (int n = 0; n < 4; n++) acc[m][n] = zero;

    int sc_[4], srow[4], sqx[4];
#pragma unroll
    for (int i = 0; i < 4; i++) {
        int c = wid * 256 + i * 64 + lane;
        sc_[i] = c; srow[i] = c >> 3; sqx[i] = (c & 7) ^ ((c >> 3) & 7);
    }
#define STAGE_AB(BUF, K0)                                                      \
    {                                                                          \
        _Pragma("unroll") for (int i = 0; i < 4; i++) {                        \
            gl16(&A[(size_t)(m0 + srow[i]) * 1024 + (K0) + sqx[i] * 8],        \
                 (void*)&As[BUF][sc_[i] * 8]);                                 \
            gl16(&Bt[(size_t)(n0 + srow[i]) * 1024 + (K0) + sqx[i] * 8],       \
                 (void*)&Bs[BUF][sc_[i] * 8]);                                 \
        }                                                                      \
    }

    STAGE_AB(0, 0);
    __syncthreads();
    int cur = 0;
    for (int k0 = 0; k0 < 1024; k0 += 64) {
        if (k0 < 960) STAGE_AB(cur ^ 1, k0 + 64);
#pragma unroll
        for (int kk = 0; kk < 2; kk++) {
            bf16x8 af[4], bfr[4];
#pragma unroll
            for (int m = 0; m < 4; m++) {
                int row = wr * 64 + m * 16 + lr;
                af[m] = *(const bf16x8*)(AsB + cur * BUFSZ +
                                         ((row * 128 + kk * 64 + lg * 16) ^ ((row & 7) << 4)));
            }
#pragma unroll
            for (int n = 0; n < 4; n++) {
                int row = wc * 64 + n * 16 + lr;
                bfr[n] = *(const bf16x8*)(BsB + cur * BUFSZ +
                                          ((row * 128 + kk * 64 + lg * 16) ^ ((row & 7) << 4)));
            }
#pragma unroll
            for (int m = 0; m < 4; m++)
#pragma unroll
                for (int n = 0; n < 4; n++) acc[m][n] = mfma16(af[m], bfr[n], acc[m][n]);
        }
        __syncthreads();
        cur ^= 1;
    }
#undef STAGE_AB
#pragma unroll
    for (int n = 0; n < 4; n++) {
        int colg = n0 + wc * 64 + n * 16 + lr;
        int mk = (z == 1) ? mask[colg] : 0;
#pragma unroll
        for (int m = 0; m < 4; m++) {
            int rowg = m0 + wr * 64 + m * 16 + lg * 4;
#pragma unroll
            for (int j = 0; j < 4; j++) {
                float v = acc[m][n][j];
                size_t idx = (size_t)(rowg + j) * 1024 + colg;
                if (z == 0) C[idx] = v;
                else C[idx] = mk ? NEGV : v * (1.f / 16.f);
            }
        }
    }
}

// ---------------------------------------------------------------------------
// Flash attention v4 (unchanged): per (b, h, 64-row q-tile), KVBLK=64,
// swapped QK^T, exp2-domain softmax, row-XOR swizzled LDS.
// ---------------------------------------------------------------------------
__global__ __launch_bounds__(256, 4) void flash_k(const bf16* __restrict__ Q,
                                                  const bf16* __restrict__ K,
                                                  const bf16* __restrict__ VT,
                                                  bf16* __restrict__ CTX,
                                                  const int* __restrict__ maskp) {
    __shared__ bf16 Ks[64 * 64];
    __shared__ bf16 Vs[64 * 64];
    __shared__ bf16 Ps[4][16 * 64];
    __shared__ float biasS[1024];
    int bid = blockIdx.x;
    int qt = bid & 15, h = (bid >> 4) & 15, b = bid >> 8;
    int t = threadIdx.x, wid = t >> 6, lane = t & 63;
    int lr = lane & 15, lg = lane >> 4;
    int qbase = qt * 64 + wid * 16;
    const size_t bS = (size_t)b * 1024;
    char* KsB = (char*)Ks;
    char* VsB = (char*)Vs;
    char* PsW = (char*)&Ps[wid][0];
    const int sxl = (lr & 7) << 4;

    {
        int4 mv = *(const int4*)&maskp[b * 1024 + t * 4];
        float4 bv;
        const float NB = NEGV * LOG2E;
        bv.x = mv.x ? NB : 0.f; bv.y = mv.y ? NB : 0.f;
        bv.z = mv.z ? NB : 0.f; bv.w = mv.w ? NB : 0.f;
        *(float4*)&biasS[t * 4] = bv;
    }

    bf16x8 qf[2];
#pragma unroll
    for (int c = 0; c < 2; c++)
        qf[c] = *(const bf16x8*)&Q[(bS + qbase + lr) * 1024 + h * 64 + c * 32 + lg * 8];

    f32x4 zero = {0.f, 0.f, 0.f, 0.f};
    f32x4 acc[4];
#pragma unroll
    for (int d = 0; d < 4; d++) acc[d] = zero;
    float mr = -INFINITY;
    float lsum = 0.f;

    const bf16* Kbase = K + bS * 1024 + h * 64;
    const bf16* Vbase = VT + (size_t)(h * 64) * 4096 + bS;

    int c0 = t, c1 = t + 256;
    int kr0 = c0 >> 3, kq0 = c0 & 7, kr1 = c1 >> 3, kq1 = c1 & 7;

    bf16x8 kg[2], vg[2];
    kg[0] = *(const bf16x8*)&Kbase[(size_t)kr0 * 1024 + kq0 * 8];
    kg[1] = *(const bf16x8*)&Kbase[(size_t)kr1 * 1024 + kq1 * 8];
    vg[0] = *(const bf16x8*)&Vbase[(size_t)kr0 * 4096 + kq0 * 8];
    vg[1] = *(const bf16x8*)&Vbase[(size_t)kr1 * 4096 + kq1 * 8];

    for (int kt = 0; kt < 16; kt++) {
        __syncthreads();
        *(bf16x8*)(KsB + ((kr0 * 128 + kq0 * 16) ^ ((kr0 & 7) << 4))) = kg[0];
        *(bf16x8*)(KsB + ((kr1 * 128 + kq1 * 16) ^ ((kr1 & 7) << 4))) = kg[1];
        *(bf16x8*)(VsB + ((kr0 * 128 + kq0 * 16) ^ ((kr0 & 7) << 4))) = vg[0];
        *(bf16x8*)(VsB + ((kr1 * 128 + kq1 * 16) ^ ((kr1 & 7) << 4))) = vg[1];
        __syncthreads();
        if (kt < 15) {
            size_t ko = (size_t)(kt + 1) * 64;
            kg[0] = *(const bf16x8*)&Kbase[(ko + kr0) * 1024 + kq0 * 8];
            kg[1] = *(const bf16x8*)&Kbase[(ko + kr1) * 1024 + kq1 * 8];
            vg[0] = *(const bf16x8*)&Vbase[(size_t)kr0 * 4096 + ko + kq0 * 8];
            vg[1] = *(const bf16x8*)&Vbase[(size_t)kr1 * 4096 + ko + kq1 * 8];
        }
        f32x4 s[4];
        __builtin_amdgcn_s_setprio(1);
#pragma unroll
        for (int n = 0; n < 4; n++) {
            int row = n * 16 + lr;
            bf16x8 kf0 = *(const bf16x8*)(KsB + ((row * 128 + lg * 16) ^ sxl));
            bf16x8 kf1 = *(const bf16x8*)(KsB + ((row * 128 + 64 + lg * 16) ^ sxl));
            f32x4 zz = zero;
            zz = mfma16(kf0, qf[0], zz);
            zz = mfma16(kf1, qf[1], zz);
            s[n] = zz;
        }
        __builtin_amdgcn_s_setprio(0);
#pragma unroll
        for (int n = 0; n < 4; n++) {
            float4 bv = *(const float4*)&biasS[kt * 64 + n * 16 + lg * 4];
            s[n][0] = __builtin_fmaf(s[n][0], LOG2E, bv.x);
            s[n][1] = __builtin_fmaf(s[n][1], LOG2E, bv.y);
            s[n][2] = __builtin_fmaf(s[n][2], LOG2E, bv.z);
            s[n][3] = __builtin_fmaf(s[n][3], LOG2E, bv.w);
        }
        float pm;
        {
            float a0 = fmaxf(fmaxf(s[0][0], s[0][1]), fmaxf(s[0][2], s[0][3]));
            float a1 = fmaxf(fmaxf(s[1][0], s[1][1]), fmaxf(s[1][2], s[1][3]));
            float a2 = fmaxf(fmaxf(s[2][0], s[2][1]), fmaxf(s[2][2], s[2][3]));
            float a3 = fmaxf(fmaxf(s[3][0], s[3][1]), fmaxf(s[3][2], s[3][3]));
            pm = fmaxf(fmaxf(a0, a1), fmaxf(a2, a3));
        }
        pm = fmaxf(pm, __shfl_xor(pm, 16));
        pm = fmaxf(pm, __shfl_xor(pm, 32));
        float mn = fmaxf(mr, pm);
        float sc = __builtin_exp2f(mr - mn);
        mr = mn;
        float rs;
        {
            float r0 = 0.f, r1 = 0.f, r2 = 0.f, r3 = 0.f;
#pragma unroll
            for (int n = 0; n < 4; n++) {
                float p0 = __builtin_exp2f(s[n][0] - mn);
                float p1 = __builtin_exp2f(s[n][1] - mn);
                float p2 = __builtin_exp2f(s[n][2] - mn);
                float p3 = __builtin_exp2f(s[n][3] - mn);
                s[n][0] = p0; s[n][1] = p1; s[n][2] = p2; s[n][3] = p3;
                r0 += p0; r1 += p1; r2 += p2; r3 += p3;
            }
            rs = (r0 + r1) + (r2 + r3);
        }
        rs += __shfl_xor(rs, 16);
        rs += __shfl_xor(rs, 32);
        lsum = lsum * sc + rs;
        float scb[4];
#pragma unroll
        for (int j = 0; j < 4; j++) scb[j] = __shfl(sc, lg * 4 + j);
#pragma unroll
        for (int d = 0; d < 4; d++) {
            acc[d][0] *= scb[0]; acc[d][1] *= scb[1];
            acc[d][2] *= scb[2]; acc[d][3] *= scb[3];
        }
#pragma unroll
        for (int n = 0; n < 4; n++) {
            bf16x4 o;
            o[0] = (bf16)s[n][0]; o[1] = (bf16)s[n][1];
            o[2] = (bf16)s[n][2]; o[3] = (bf16)s[n][3];
            *(bf16x4*)(PsW + ((lr * 128 + n * 32 + lg * 8) ^ sxl)) = o;
        }
        __builtin_amdgcn_s_setprio(1);
#pragma unroll
        for (int c = 0; c < 2; c++) {
            bf16x8 pa = *(const bf16x8*)(PsW + ((lr * 128 + c * 64 + lg * 16) ^ sxl));
#pragma unroll
            for (int d = 0; d < 4; d++) {
                int row = d * 16 + lr;
                bf16x8 vb = *(const bf16x8*)(VsB + ((row * 128 + c * 64 + lg * 16) ^ ((row & 7) << 4)));
                acc[d] = mfma16(pa, vb, acc[d]);
            }
        }
        __builtin_amdgcn_s_setprio(0);
    }
    float lb[4];
#pragma unroll
    for (int j = 0; j < 4; j++) lb[j] = __shfl(lsum, lg * 4 + j);
#pragma unroll
    for (int j = 0; j < 4; j++) {
        float inv = 1.f / lb[j];
#pragma unroll
        for (int d = 0; d < 4; d++)
            CTX[(bS + qbase + lg * 4 + j) * 1024 + h * 64 + d * 16 + lr] = f2b(acc[d][j] * inv);
    }
}

extern "C" void kernel_launch(void* const* d_in, const int* in_sizes, int n_in,
                              void* d_out, int out_size, void* d_ws, size_t ws_size,
                              hipStream_t stream) {
    const float* queries = (const float*)d_in[0];
    const float* keys    = (const float*)d_in[1];
    const float* values  = (const float*)d_in[2];
    const float* Wq = (const float*)d_in[3];
    const float* Wk = (const float*)d_in[4];
    const float* Wv = (const float*)d_in[5];
    const float* Wo = (const float*)d_in[6];
    const int* mask = (const int*)d_in[7];

    float* out = (float*)d_out;                       // [4,1024,1024]
    float* aw  = out + ((size_t)4 << 20);             // [4,1024,1024]

    bf16* wsb = (bf16*)d_ws;
    bf16* WtQ = wsb;                                  // [0,4M) transposed weights (Q,K,V,O)
    bf16* Qw  = wsb + ((size_t)4 << 20);
    bf16* Kw  = wsb + ((size_t)8 << 20);
    bf16* VtG = wsb + ((size_t)12 << 20);             // [1024][4096] V transposed
    bf16* CTX = wsb + ((size_t)16 << 20);

    wconv<<<dim3(16, 16, 4), 256, 0, stream>>>(Wq, Wk, Wv, Wo, WtQ);
    gemm_proj<<<dim3(32, 8, 3), 256, 0, stream>>>(queries, keys, values, WtQ, Qw, Kw, VtG);
    flash_k<<<dim3(1024), 256, 0, stream>>>(Qw, Kw, VtG, CTX, mask);
    gemm_oa<<<dim3(32, 8, 2), 256, 0, stream>>>(CTX, WtQ + ((size_t)3 << 20), out,
                                                Qw, Kw, aw, mask);
}